// Round 11
// baseline (486.833 us; speedup 1.0000x reference)
//
#include <hip/hip_runtime.h>
#include <cstddef>
#include <cstdint>

#define BATCH_N 32768
#define OUT_DIM 10
#define HS 524288   // partial-buffer stride in floats (8 matrices x 65536)

typedef unsigned short u16;
typedef __attribute__((ext_vector_type(8))) _Float16 half8;
typedef __attribute__((ext_vector_type(4))) float f32x4;
typedef __attribute__((ext_vector_type(16))) float f32x16;

__device__ __forceinline__ u16 f2h(float v) {
    _Float16 h = (_Float16)v;                 // RTN
    return __builtin_bit_cast(u16, h);
}
__device__ __forceinline__ float h2f(u16 h) {
    return (float)__builtin_bit_cast(_Float16, h);
}
__device__ __forceinline__ float tanh_fast(float x) {
    float e = __expf(2.f * x);        // inf -> 1, 0 -> -1 : robust
    return 1.f - 2.f / (e + 1.f);
}

// async global->LDS, 16B per lane: dest = lds_base + lane*16 (wave-uniform base)
__device__ __forceinline__ void gload_lds16(const u16* g, u16* l) {
    __builtin_amdgcn_global_load_lds(
        (const __attribute__((address_space(1))) uint32_t*)g,
        (__attribute__((address_space(3))) uint32_t*)l, 16, 0, 0);
}

// ============================================================================
// MEGA-FUSED NETWORK KERNEL (R17: LDS-staged B weights via global_load_lds).
// Evidence R8<->R16: time invariant while LDS reads halved and L2-B traffic
// doubled -> B-weight path (L2 BW + depth-1 latency chain) is the binding
// constraint, not LDS.  Fix: 16 waves each DMA their tile's 1KB ks-slice into
// a double-buffered 2x16KB LDS region (one global_load_lds(16) per wave/ks):
// dedups rg-pair loads (1MB -> 512KB /CU/layer) and makes the weight stream
// async (whole-ks compute covers it; __syncthreads' vmcnt drain publishes).
// B from LDS frees the 16-VGPR ping-pong -> fits the hard 128-reg budget.
// LDS: 128KB state + 32KB bwt = 160KB exact (x-staging overlays bwt).
// State layout: elem (m,k) at (k>>4)*2048+(m>>5)*512+((k>>3)&1)*256+(m&31)*8+(k&7).
// Wc layout: [L][tile 0..15][ks 0..31][512]; tile w loaded by wave w.
// ============================================================================
__global__ __launch_bounds__(1024, 4)
void meganet(const float* __restrict__ X,
             const u16* __restrict__ Wi,        // [256 u][800 k] f16
             const float* __restrict__ b_in,
             const u16* __restrict__ Wc,        // [8][16][32][512] f16
             const float* __restrict__ cc,      // [8][512]: [0..255]=c0, [256..511]=c1
             const u16* __restrict__ WoT,       // [16 ks][512] f16 B-frag pack
             const float* __restrict__ bo,
             float* __restrict__ out)
{
    __shared__ u16 state[65536];     // 128 KB
    __shared__ u16 bwt[16384];       // 32 KB: B double-buffer; x-staging overlay
    const int t = threadIdx.x;
    const int wave = t >> 6, lane = t & 63;
    const int fl = lane & 15, kq = lane >> 4;
    const int b0 = blockIdx.x * 128;

    // ---------------- input stage: v0 = x @ W_in + b_in (K=784, pad 800) ----
    f32x4 ai[8];
#pragma unroll
    for (int a = 0; a < 8; ++a) ai[a] = (f32x4){0.f, 0.f, 0.f, 0.f};

    const u16* bpIn = Wi + (size_t)(wave * 16 + fl) * 800 + kq * 8;

    u16* xbuf = bwt;                 // 2 x 4096 u16 chunk buffers (16 KB)
    const int xr = t >> 3;           // row 0..127
    const int xk = (t & 7) * 4;      // 0..28 step 4
    const size_t xrow = (size_t)(b0 + xr) * 784;
    const int xoff = (xr >> 4) * 512 + ((xk >> 3) * 16 + (xr & 15)) * 8 + (xk & 7);

    half8 IB[2];
    float4 xa;
    {   // prologue: chunk0 -> buf0
        float4 x0 = *(const float4*)(X + xrow + xk);
        ushort4 h;
        h.x = f2h(x0.x); h.y = f2h(x0.y); h.z = f2h(x0.z); h.w = f2h(x0.w);
        *(ushort4*)&xbuf[xoff] = h;
        xa = *(const float4*)(X + xrow + 32 + xk);     // chunk 1
        IB[0] = *(const half8*)(bpIn);                 // chunk 0 weights
    }

#pragma unroll
    for (int ki = 0; ki < 25; ++ki) {
        const int cur = ki & 1, nxt = cur ^ 1;
        __syncthreads();                 // buf[cur] ready; buf[nxt] reads done
        if (ki < 24) {                   // stage chunk ki+1 into buf[nxt]
            ushort4 h;
            h.x = f2h(xa.x); h.y = f2h(xa.y); h.z = f2h(xa.z); h.w = f2h(xa.w);
            *(ushort4*)&xbuf[nxt * 4096 + xoff] = h;
            if (ki < 23) {               // load chunk ki+2 (depth-2)
                const int gk = (ki + 2) * 32 + xk;
                const int ga = (gk <= 780) ? gk : 780;   // Wi packs 0 for k>=784
                xa = *(const float4*)(X + xrow + ga);
            }
            IB[nxt] = *(const half8*)(bpIn + (ki + 1) * 32);
        }
        const u16* rb = xbuf + cur * 4096;
#pragma unroll
        for (int mt = 0; mt < 8; ++mt) {
            half8 af = *(const half8*)&rb[mt * 512 + lane * 8];
            ai[mt] = __builtin_amdgcn_mfma_f32_16x16x32_f16(af, IB[cur], ai[mt], 0, 0, 0);
        }
    }

    const int rg = wave >> 3, cg = wave & 7;
    const int cl = lane & 31, lh = lane >> 5;

    // xbuf reads done; issue L0 slice0 DMA into bwt buf0 (overlaps epilogue)
    __syncthreads();
    const u16* wsrc = Wc + (size_t)wave * 16384 + lane * 8;  // tile = wave
    gload_lds16(wsrc, bwt + wave * 512);

    // input epilogue: state v0 (k=u), w = 2*tanh(v0) (k=256+u)
    {
        const float bi = b_in[wave * 16 + fl];
        const int u = wave * 16 + fl;
        const int A0 = (u >> 4) * 2048 + ((u >> 3) & 1) * 256 + (u & 7);
#pragma unroll
        for (int mt = 0; mt < 8; ++mt) {
#pragma unroll
            for (int r = 0; r < 4; ++r) {
                float v = ai[mt][r] + bi;
                float w = 2.f * tanh_fast(v);
                const int addr = A0 + (mt >> 1) * 512 +
                                 ((mt & 1) * 16 + kq * 4 + r) * 8;
                state[addr] = f2h(v);
                state[addr + 32768] = f2h(w);
            }
        }
    }

    // ---------------- 8 implicit layers (32x32x16, LDS-staged B) ------------
    const int uu = cg * 32 + cl;          // this lane's output column u
    const int A0e = (uu >> 4) * 2048 + ((uu >> 3) & 1) * 256 + (uu & 7);
    for (int L = 0; L < 8; ++L) {
        const float ccv0 = cc[L * 512 + uu];
        const float ccv1 = cc[L * 512 + 256 + uu];
        f32x16 acc00, acc01, acc10, acc11;
#pragma unroll
        for (int j = 0; j < 16; ++j) {
            acc00[j] = 0.f; acc01[j] = 0.f; acc10[j] = 0.f; acc11[j] = 0.f;
        }
#pragma unroll
        for (int ks = 0; ks < 32; ++ks) {
            const int cur = ks & 1;
            // publish buf[cur] (DMA'd last iter; vmcnt drained by barrier)
            // and, at ks==0, the previous epilogue's state writes
            __syncthreads();
            if (ks < 31) {               // DMA next slice into buf[cur^1]
                gload_lds16(wsrc + (ks + 1) * 512, bwt + (cur ^ 1) * 8192 + wave * 512);
            } else if (L < 7) {          // DMA next layer's slice0 (lands by L+1 ks0)
                gload_lds16(wsrc + 262144, bwt + (cur ^ 1) * 8192 + wave * 512);
            }
            half8 b0 = *(const half8*)&bwt[cur * 8192 + cg * 512 + lane * 8];
            half8 b1 = *(const half8*)&bwt[cur * 8192 + (8 + cg) * 512 + lane * 8];
            half8 af0 = *(const half8*)&state[ks * 2048 + (rg * 2 + 0) * 512 + lane * 8];
            half8 af1 = *(const half8*)&state[ks * 2048 + (rg * 2 + 1) * 512 + lane * 8];
            acc00 = __builtin_amdgcn_mfma_f32_32x32x16_f16(af0, b0, acc00, 0, 0, 0);
            acc10 = __builtin_amdgcn_mfma_f32_32x32x16_f16(af1, b0, acc10, 0, 0, 0);
            acc01 = __builtin_amdgcn_mfma_f32_32x32x16_f16(af0, b1, acc01, 0, 0, 0);
            acc11 = __builtin_amdgcn_mfma_f32_32x32x16_f16(af1, b1, acc11, 0, 0, 0);
        }
        if (L == 7) wsrc += 262144; else wsrc += 262144;   // advance to next layer
        __syncthreads();   // all state reads done; safe to overwrite
        // epilogue: lane owns col u for rows rg*64..+63; z0/z1 in-thread
#pragma unroll
        for (int rt = 0; rt < 2; ++rt) {
#pragma unroll
            for (int j = 0; j < 16; ++j) {
                const int rowt = (j & 3) + 8 * (j >> 2) + 4 * lh;
                const int addr = A0e + (rg * 2 + rt) * 512 + rowt * 8;
                float z0 = (rt ? acc10[j] : acc00[j]) + ccv0;
                float z1 = (rt ? acc11[j] : acc01[j]) + ccv1;
                float tv = tanh_fast(z0);
                state[addr] = f2h(z0);
                state[addr + 32768] = f2h(z1 + tv);
            }
        }
    }

    // ---------------- output stage: out = v0 @ W_out + b_out (32x32x16) ----
    __syncthreads();
    if (wave < 4) {
        f32x16 oa;
#pragma unroll
        for (int j = 0; j < 16; ++j) oa[j] = 0.f;
        const u16* wp = WoT + lane * 8;
#pragma unroll
        for (int ks = 0; ks < 16; ++ks) {          // v0 = state k<256
            half8 af = *(const half8*)&state[ks * 2048 + wave * 512 + lane * 8];
            half8 bf = *(const half8*)(wp + ks * 512);
            oa = __builtin_amdgcn_mfma_f32_32x32x16_f16(af, bf, oa, 0, 0, 0);
        }
        if (cl < 10) {
            const float bv = bo[cl];
#pragma unroll
            for (int j = 0; j < 16; ++j) {
                const int m = wave * 32 + (j & 3) + 8 * (j >> 2) + 4 * lh;
                out[(size_t)(b0 + m) * 10 + cl] = oa[j] + bv;
            }
        }
    }
}

// ============================================================================
// Prep — R16 verbatim (pinned ~215us; Wc tile-layout pack verified correct).
// ============================================================================

template<int NS>
__device__ __forceinline__ float4 ldn(const float* __restrict__ p, size_t idx) {
    float4 v = *(const float4*)(p + idx);
#pragma unroll
    for (int s = 1; s < NS; ++s) {
        float4 w = *(const float4*)(p + idx + (size_t)s * HS);
        v.x += w.x; v.y += w.y; v.z += w.z; v.w += w.w;
    }
    return v;
}

template<int EPI, int KLEN, int AS, int BS, int ES, int E2S>
__device__ __forceinline__ void gemm_body(float* __restrict__ D,
        const float* __restrict__ A, const float* __restrict__ Bm,
        const float* __restrict__ E, const float* __restrict__ E2,
        const float* __restrict__ scr_r, float* __restrict__ scr_w,
        int i, int u0, int v0, int kh)
{
    __shared__ float As[16][64];
    __shared__ float Bs[16][64];
    const size_t off = (size_t)i * 65536;
    const int t  = threadIdx.x;
    const int tx = t & 15, ty = t >> 4;
    const int lk = t >> 4, lv = (t & 15) << 2;

    float ca = 0.f, cb = 0.f;
    if (EPI == 3 || EPI == 4) {        // NS seed coefficients from rowsum parts
        float* red = &As[0][0];
        {
            float s = scr_r[i * 1024 + t];
#pragma unroll
            for (int vt = 1; vt < 4; ++vt) s += scr_r[i * 1024 + vt * 256 + t];
            red[t] = s;
        }
        __syncthreads();
        for (int o = 128; o >= 1; o >>= 1) {
            if (t < o) red[t] = fmaxf(red[t], red[t + o]);
            __syncthreads();
        }
        const float bt_ = red[0];                  // >= lambda_max; lambda_min >= 2
        const float r = (2.f + bt_) * (2.f + bt_) / (8.f * bt_);
        const float e = (r - 1.f) / (r + 1.f);
        cb = -(1.f - e) / (2.f * bt_);
        ca = -cb * (2.f + bt_);
        __syncthreads();
    }

    const int kb = kh * KLEN;
    float acc[4][4];
#pragma unroll
    for (int m = 0; m < 4; ++m)
#pragma unroll
        for (int n = 0; n < 4; ++n) acc[m][n] = 0.f;

    float4 an = ldn<AS>(A, off + (size_t)(kb + lk) * 256 + u0 + lv);
    float4 bn = ldn<BS>(Bm, off + (size_t)(kb + lk) * 256 + v0 + lv);

    for (int k0 = 0; k0 < KLEN; k0 += 16) {
        if (k0) __syncthreads();
        *(float4*)&As[lk][lv] = an;
        *(float4*)&Bs[lk][lv] = bn;
        if (k0 < KLEN - 16) {
            an = ldn<AS>(A, off + (size_t)(kb + k0 + 16 + lk) * 256 + u0 + lv);
            bn = ldn<BS>(Bm, off + (size_t)(kb + k0 + 16 + lk) * 256 + v0 + lv);
        }
        __syncthreads();
#pragma unroll
        for (int kk = 0; kk < 16; ++kk) {
            float af[4], bf[4];
            *(float4*)&af[0] = *(const float4*)&As[kk][ty * 4];
            *(float4*)&bf[0] = *(const float4*)&Bs[kk][tx * 4];
#pragma unroll
            for (int m = 0; m < 4; ++m)
#pragma unroll
                for (int n = 0; n < 4; ++n) acc[m][n] += af[m] * bf[n];
        }
    }

    float* Dp = D + (size_t)kh * HS;
#pragma unroll
    for (int m = 0; m < 4; ++m) {
        const int u = u0 + ty * 4 + m;
        const size_t idx = off + (size_t)u * 256 + v0 + tx * 4;
        float4 r; float* rf = &r.x;
        if (EPI == 0) {
#pragma unroll
            for (int n = 0; n < 4; ++n) rf[n] = acc[m][n];
        } else if (EPI == 1) {
#pragma unroll
            for (int n = 0; n < 4; ++n)
                rf[n] = acc[m][n] + ((u == v0 + tx * 4 + n) ? 2.f : 0.f);
        } else if (EPI == 2) {
            if (kh == 0) {
                float4 e4 = ldn<ES>(E, idx); const float* ef = &e4.x;
#pragma unroll
                for (int n = 0; n < 4; ++n) rf[n] = 2.f * ef[n] - acc[m][n];
            } else {
#pragma unroll
                for (int n = 0; n < 4; ++n) rf[n] = -acc[m][n];
            }
        } else if (EPI == 3) {
            if (kh == 0) {
                float4 e4 = ldn<ES>(E, idx); const float* ef = &e4.x;
#pragma unroll
                for (int n = 0; n < 4; ++n) rf[n] = ca * ef[n] + cb * acc[m][n];
            } else {
#pragma unroll
                for (int n = 0; n < 4; ++n) rf[n] = cb * acc[m][n];
            }
        } else {   // EPI 4
            if (kh == 0) {
                float4 e4 = ldn<ES>(E, idx); const float* ef = &e4.x;
                float4 f4 = ldn<E2S>(E2, idx); const float* ff = &f4.x;
#pragma unroll
                for (int n = 0; n < 4; ++n)
                    rf[n] = 2.f * ca * ((u == v0 + tx * 4 + n) ? 1.f : 0.f)
                          + 2.f * cb * ef[n] - ca * ff[n] - cb * acc[m][n];
            } else {
#pragma unroll
                for (int n = 0; n < 4; ++n) rf[n] = -cb * acc[m][n];
            }
        }
        *(float4*)&Dp[idx] = r;
        if (EPI == 1) {                // Gershgorin rowsum partial (plain store)
            float s = fabsf(rf[0]) + fabsf(rf[1]) + fabsf(rf[2]) + fabsf(rf[3]);
            s += __shfl_xor(s, 1); s += __shfl_xor(s, 2);
            s += __shfl_xor(s, 4); s += __shfl_xor(s, 8);
            if (tx == 0) scr_w[(i * 4 + (v0 >> 6)) * 256 + u] = s;
        }
    }
}

// K1: C = B0^T B0 + 2I (unsplit, rowsum parts) | Bt | Wi pack | WoT pack
__launch_bounds__(256)
__global__ void k1_fused(const float* __restrict__ B0, const float* __restrict__ W_in,
                         const float* __restrict__ W_out,
                         float* __restrict__ C, float* __restrict__ Bt,
                         u16* __restrict__ Wi, u16* __restrict__ WoT,
                         float* __restrict__ scr)
{
    const int b = blockIdx.x;
    const int t = threadIdx.x;
    if (b < 128) {
        const int i = b >> 4, tile = b & 15;
        gemm_body<1, 256, 1, 1, 1, 1>(C, B0, B0, nullptr, nullptr,
                                      nullptr, scr, i,
                                      (tile >> 2) * 64, (tile & 3) * 64, 0);
        return;
    }
    __shared__ float tl[32][33];
    const int tx = t & 31, ty = t >> 5;   // 32 x 8
    if (b < 192) {                        // Bt transpose: 64 blocks
        const int bb = b - 128;
        const int i = bb >> 3;
        const size_t off = (size_t)i * 65536;
        const int u0 = (bb & 7) * 32;
        for (int k0 = 0; k0 < 256; k0 += 32) {
            __syncthreads();
#pragma unroll
            for (int r = 0; r < 32; r += 8)
                tl[ty + r][tx] = B0[off + (size_t)(u0 + ty + r) * 256 + k0 + tx];
            __syncthreads();
#pragma unroll
            for (int r = 0; r < 32; r += 8)
                Bt[off + (size_t)(k0 + ty + r) * 256 + u0 + tx] = tl[tx][ty + r];
        }
    } else if (b < 392) {                 // Wi pack: 200 blocks
        const int bb = b - 192;           // 25 k-tiles x 8 u-tiles
        const int k0 = (bb % 25) * 32, u0 = (bb / 25) * 32;
#pragma unroll
        for (int r = 0; r < 32; r += 8) {
            const int k = k0 + ty + r;
            tl[ty + r][tx] = (k < 784) ? W_in[(size_t)k * 256 + u0 + tx] : 0.f;
        }
        __syncthreads();
#pragma unroll
        for (int r = 0; r < 32; r += 8)
            Wi[(size_t)(u0 + ty + r) * 800 + k0 + tx] = f2h(tl[tx][ty + r]);
    } else {                              // WoT pack: [16 ks][512] B-frag order
        for (int idx = t; idx < 8192; idx += 256) {
            const int ks = idx >> 9, rr = idx & 511;
            const int l = rr >> 3, j = rr & 7;
            const int col = l & 31;
            const int k = ks * 16 + (l >> 5) * 8 + j;
            WoT[idx] = f2h((col < 10) ? W_out[(size_t)k * 10 + col] : 0.f);
        }
    }
}

// split GEMM dispatch: grid (4,4,32), z = matrix(0..7) + 8*kq (kq 0..3), K=64
template<int EPI, int AS, int BS, int ES, int E2S>
__launch_bounds__(256)
__global__ void gemmS(float* __restrict__ D, const float* __restrict__ A,
                      const float* __restrict__ Bm, const float* __restrict__ E,
                      const float* __restrict__ E2, const float* __restrict__ scr)
{
    const int z = blockIdx.z;
    gemm_body<EPI, 64, AS, BS, ES, E2S>(D, A, Bm, E, E2, scr, nullptr,
                                        z & 7, blockIdx.y * 64, blockIdx.x * 64,
                                        z >> 3);
}

// PQcc: z<16: P = M Bt (split2) | z 16..31: Q = B M (split2) | z==32: cc
__launch_bounds__(256)
__global__ void gemmPQcc(float* __restrict__ bufPQ, const float* __restrict__ M,
                         const float* __restrict__ Bt, const float* __restrict__ B0,
                         const float* __restrict__ q, float* __restrict__ cc)
{
    const int z = blockIdx.z;
    if (z < 16) {
        gemm_body<0, 128, 4, 1, 1, 1>(bufPQ, M, Bt, nullptr, nullptr, nullptr,
                nullptr, z & 7, blockIdx.y * 64, blockIdx.x * 64, (z >> 3) & 1);
        return;
    }
    if (z < 32) {
        const int zz = z - 16;
        gemm_body<0, 128, 1, 4, 1, 1>(bufPQ + 2 * (size_t)HS, Bt, M, nullptr,
                nullptr, nullptr, nullptr, zz & 7,
                blockIdx.y * 64, blockIdx.x * 64, (zz >> 3) & 1);
        return;
    }
    if (blockIdx.y != 0 || blockIdx.x >= 8) return;
    __shared__ float qs[256];
    __shared__ float vs[256];
    __shared__ float c1s[256];
    const int i = blockIdx.x;
    const int u = threadIdx.x;
    const size_t ob = (size_t)i * 65536;
    qs[u] = q[i * 256 + u];
    __syncthreads();
    float s0 = 0.f;
    for (int k = 0; k < 256; ++k) s0 += B0[ob + (size_t)k * 256 + u] * qs[k];
    vs[u] = 0.1f * s0;
    __syncthreads();
    float s = 0.f;
    for (int k = 0; k < 256; ++k) {
        const size_t mi = ob + (size_t)k * 256 + u;
        s += (M[mi] + M[mi + HS] + M[mi + 2 * (size_t)HS] + M[mi + 3 * (size_t)HS]) * vs[k];
    }
    c1s[u] = s;
    cc[i * 512 + 256 + u] = s;
    __syncthreads();
    float s2 = 0.f;
    for (int k = 0; k < 256; ++k) s2 += Bt[ob + (size_t)k * 256 + u] * c1s[k];
    cc[i * 512 + u] = 0.1f * qs[u] - s2;
}

// Wc pack into the tile layout; sums partials (P s2, Q s2, R s4, M s4)
__launch_bounds__(256)
__global__ void pack_wcomb(const float* __restrict__ P, const float* __restrict__ Q,
                           const float* __restrict__ R, const float* __restrict__ M,
                           u16* __restrict__ W)
{
    const int i = blockIdx.y;
    const int e = blockIdx.x * 256 + threadIdx.x;   // 0..262143
    const int c = e >> 9, k = e & 511;
    const size_t off = (size_t)i * 65536;
    float v;
    if (c < 256) {        // z0 row u=c: [I - R | -Q]
        if (k < 256) {
            const size_t idx = off + (size_t)c * 256 + k;
            v = ((c == k) ? 1.f : 0.f)
              - (R[idx] + R[idx + HS] + R[idx + 2 * (size_t)HS] + R[idx + 3 * (size_t)HS]);
        } else {
            const size_t idx = off + (size_t)c * 256 + (k - 256);
            v = -(Q[idx] + Q[idx + HS]);
        }
    } else {              // z1 row u=c-256: [P | M]
        const int u = c - 256;
        if (k < 256) {
            const size_t idx = off + (size_t)u * 256 + k;
            v = P[idx] + P[idx + HS];
        } else {
            const size_t idx = off + (size_t)u * 256 + (k - 256);
            v = M[idx] + M[idx + HS] + M[idx + 2 * (size_t)HS] + M[idx + 3 * (size_t)HS];
        }
    }
    // store at B-frag tile layout: tile = col-group (z0: c>>5, z1: 8+((c-256)>>5))
    const int tile = (c < 256) ? (c >> 5) : (8 + ((c - 256) >> 5));
    const int cl2 = c & 31;
    const size_t wadr = (size_t)i * 262144 + (size_t)tile * 16384
                      + (size_t)(k >> 4) * 512 + ((k >> 3) & 1) * 256 + cl2 * 8 + (k & 7);
    W[wadr] = f2h(v);
}

extern "C" void kernel_launch(void* const* d_in, const int* in_sizes, int n_in,
                              void* d_out, int out_size, void* d_ws, size_t ws_size,
                              hipStream_t stream)
{
    const float* x     = (const float*)d_in[0];
    const float* W_in  = (const float*)d_in[1];
    const float* b_in  = (const float*)d_in[2];
    const float* B0    = (const float*)d_in[3];
    const float* q     = (const float*)d_in[4];
    const float* W_out = (const float*)d_in[5];
    const float* b_out = (const float*)d_in[6];

    u16* Wc  = (u16*)d_ws;                 // 8 * 262144 u16 = 4 MB
    u16* Wi  = Wc + 8 * 262144;            // 256*800 u16
    u16* WoT = Wi + 204800;                // 8192 u16
    float* cc = (float*)(WoT + 8192);      // 8*512 floats
    float* F  = cc + 4096;
    float* Cm   = F;                       // unsplit (1 HS)
    float* Bt   = F + 1 * HS;              // unsplit (1 HS)
    float* bufY = F + 2 * HS;              // 4 HS: Y1 / Y2 / Y3 / {P,Q}
    float* bufXa = F + 6 * HS;             // 4 HS: X1 / M
    float* bufXb = F + 10 * HS;            // 4 HS: X2 / R
    float* scr  = F + 14 * HS;             // 8192 floats (rowsum partials)

    // K1: C = B0^T B0 + 2I (+rowsum parts) | Bt | Wi | WoT
    k1_fused<<<393, 256, 0, stream>>>(B0, W_in, W_out, Cm, Bt, Wi, WoT, scr);
    // NS iteration 1 with virtual X0 = aI + bC:
    gemmS<3, 1, 1, 1, 1><<<dim3(4, 4, 32), 256, 0, stream>>>(
        bufY, Cm, Cm, Cm, nullptr, scr);                    // Y1 = aC + bC^2
    gemmS<4, 1, 4, 1, 4><<<dim3(4, 4, 32), 256, 0, stream>>>(
        bufXa, Cm, bufY, Cm, bufY, scr);                    // X1 = 2X0 - X0*Y1
    // NS iteration 2:
    gemmS<0, 1, 4, 1, 1><<<dim3(4, 4, 32), 256, 0, stream>>>(
        bufY, Cm, bufXa, nullptr, nullptr, nullptr);        // Y2 = C*X1
    gemmS<2, 4, 4, 4, 1><<<dim3(4, 4, 32), 256, 0, stream>>>(
        bufXb, bufXa, bufY, bufXa, nullptr, nullptr);       // X2 = 2X1 - X1*Y2
    // NS iteration 3:
    gemmS<0, 1, 4, 1, 1><<<dim3(4, 4, 32), 256, 0, stream>>>(
        bufY, Cm, bufXb, nullptr, nullptr, nullptr);        // Y3 = C*X2
    gemmS<2, 4, 4, 4, 1><<<dim3(4, 4, 32), 256, 0, stream>>>(
        bufXa, bufXb, bufY, bufXb, nullptr, nullptr);       // M = 2X2 - X2*Y3
    // P = M B^T (s2) | Q = B M (s2) | cc:
    gemmPQcc<<<dim3(4, 4, 33), 256, 0, stream>>>(bufY, bufXa, Bt, B0, q, cc);
    // R = B P (s4):
    gemmS<0, 1, 2, 1, 1><<<dim3(4, 4, 32), 256, 0, stream>>>(
        bufXb, Bt, bufY, nullptr, nullptr, nullptr);        // R
    // pack (P=bufY, Q=bufY+2HS, R=bufXb, M=bufXa):
    pack_wcomb<<<dim3(1024, 8), 256, 0, stream>>>(
        bufY, bufY + 2 * (size_t)HS, bufXb, bufXa, Wc);

    // ---- the whole network in one kernel ----
    meganet<<<BATCH_N / 128, 1024, 0, stream>>>(
        x, Wi, b_in, Wc, cc, WoT, b_out, (float*)d_out);
}

// Round 12
// 451.145 us; speedup vs baseline: 1.0791x; 1.0791x over previous
//
#include <hip/hip_runtime.h>
#include <cstddef>
#include <cstdint>

#define BATCH_N 32768
#define OUT_DIM 10
#define HS 524288   // partial-buffer stride in floats (8 matrices x 65536)

typedef unsigned short u16;
typedef __attribute__((ext_vector_type(8))) _Float16 half8;
typedef __attribute__((ext_vector_type(4))) float f32x4;
typedef __attribute__((ext_vector_type(16))) float f32x16;

__device__ __forceinline__ u16 f2h(float v) {
    _Float16 h = (_Float16)v;                 // RTN
    return __builtin_bit_cast(u16, h);
}
__device__ __forceinline__ float h2f(u16 h) {
    return (float)__builtin_bit_cast(_Float16, h);
}
__device__ __forceinline__ float tanh_fast(float x) {
    float e = __expf(2.f * x);        // inf -> 1, 0 -> -1 : robust
    return 1.f - 2.f / (e + 1.f);
}

// ============================================================================
// MEGA-FUSED NETWORK KERNEL (R18: 2 blocks/CU for barrier overlap).
// Evidence R8/R16/R17: time pinned ~243us across 2x LDS-read and 2x L2-traffic
// swings -> memory paths are NOT binding; ~65% of time is block-wide barrier
// serialization at 1 block/CU (every __syncthreads idles the whole CU; the
// vmcnt/lgkmcnt drain has no co-resident work to hide it — m114 model).
// Fix: 64 rows/block, 512 threads = 8 waves, LDS 72KB -> exactly 2 blocks/CU;
// one block's MFMAs cover the other's barrier drains.  All fragment layouts,
// Wc/WoT packs, and the 32x32x16 layer loop are R16's (verified); the rg
// dimension is removed (one 64-row group per block).
// State [64 x 512] f16: elem (m,k) at
//   (k>>4)*1024 + (m>>5)*512 + ((k>>3)&1)*256 + (m&31)*8 + (k&7).
// Wc layout: [L][tile 0..15][ks 0..31][512]; tile cg = z0 cols, 8+cg = z1.
// ============================================================================
__global__ __launch_bounds__(512, 4)
void meganet(const float* __restrict__ X,
             const u16* __restrict__ Wi,        // [256 u][800 k] f16
             const float* __restrict__ b_in,
             const u16* __restrict__ Wc,        // [8][16][32][512] f16
             const float* __restrict__ cc,      // [8][512]: [0..255]=c0, [256..511]=c1
             const u16* __restrict__ WoT,       // [16 ks][512] f16 B-frag pack
             const float* __restrict__ bo,
             float* __restrict__ out)
{
    __shared__ u16 state[32768];     // 64 KB
    __shared__ u16 aux[4096];        // 8 KB: x double-buffer
    const int t = threadIdx.x;
    const int wave = t >> 6, lane = t & 63;
    const int fl = lane & 15, kq = lane >> 4;
    const int b0 = blockIdx.x * 64;

    // ---------------- input stage: v0 = x @ W_in + b_in (K=784, pad 800) ----
    // 8 waves x 32 cols (2 nt); acc[4][2]; x staged f16, double-buffered.
    f32x4 ai[4][2];
#pragma unroll
    for (int a = 0; a < 4; ++a) {
        ai[a][0] = (f32x4){0.f, 0.f, 0.f, 0.f};
        ai[a][1] = (f32x4){0.f, 0.f, 0.f, 0.f};
    }

    const u16* bpIn0 = Wi + (size_t)(wave * 32 + fl) * 800 + kq * 8;
    const u16* bpIn1 = bpIn0 + 16 * 800;

    u16* xbuf = aux;                 // 2 x 2048 u16 chunk buffers
    const int xr = t >> 3;           // row 0..63
    const int xk = (t & 7) * 4;      // 0..28 step 4
    const size_t xrow = (size_t)(b0 + xr) * 784;
    const int xoff = (xr >> 4) * 512 + ((xk >> 3) * 16 + (xr & 15)) * 8 + (xk & 7);

    half8 IB[2][2];
    float4 xa;
    {   // prologue: chunk0 -> buf0
        float4 x0 = *(const float4*)(X + xrow + xk);
        ushort4 h;
        h.x = f2h(x0.x); h.y = f2h(x0.y); h.z = f2h(x0.z); h.w = f2h(x0.w);
        *(ushort4*)&xbuf[xoff] = h;
        xa = *(const float4*)(X + xrow + 32 + xk);     // chunk 1
        IB[0][0] = *(const half8*)(bpIn0);             // chunk 0 weights
        IB[0][1] = *(const half8*)(bpIn1);
    }

#pragma unroll
    for (int ki = 0; ki < 25; ++ki) {
        const int cur = ki & 1, nxt = cur ^ 1;
        __syncthreads();                 // buf[cur] ready; buf[nxt] reads done
        if (ki < 24) {                   // stage chunk ki+1 into buf[nxt]
            ushort4 h;
            h.x = f2h(xa.x); h.y = f2h(xa.y); h.z = f2h(xa.z); h.w = f2h(xa.w);
            *(ushort4*)&xbuf[nxt * 2048 + xoff] = h;
            if (ki < 23) {               // load chunk ki+2 (depth-2)
                const int gk = (ki + 2) * 32 + xk;
                const int ga = (gk <= 780) ? gk : 780;   // Wi packs 0 for k>=784
                xa = *(const float4*)(X + xrow + ga);
            }
            IB[nxt][0] = *(const half8*)(bpIn0 + (ki + 1) * 32);
            IB[nxt][1] = *(const half8*)(bpIn1 + (ki + 1) * 32);
        }
        const u16* rb = xbuf + cur * 2048;
#pragma unroll
        for (int mt = 0; mt < 4; ++mt) {
            half8 af = *(const half8*)&rb[mt * 512 + lane * 8];
            ai[mt][0] = __builtin_amdgcn_mfma_f32_16x16x32_f16(af, IB[cur][0], ai[mt][0], 0, 0, 0);
            ai[mt][1] = __builtin_amdgcn_mfma_f32_16x16x32_f16(af, IB[cur][1], ai[mt][1], 0, 0, 0);
        }
    }

    // layer-0 ks=0 weight prefetch (Wc tile layout): tile = wave (z0), 8+wave (z1)
    const int cl = lane & 31, lh = lane >> 5;
    const u16* bp0 = Wc + (size_t)wave * 16384 + lane * 8;
    const u16* bp1 = bp0 + 8 * 16384;
    half8 B[2][2];
    B[0][0] = *(const half8*)bp0;
    B[0][1] = *(const half8*)bp1;

    // input epilogue: state v0 (k=u), w = 2*tanh(v0) (k=256+u)
#pragma unroll
    for (int nt = 0; nt < 2; ++nt) {
        const int u = wave * 32 + nt * 16 + fl;
        const float bi = b_in[u];
        const int A0i = (u >> 4) * 1024 + ((u >> 3) & 1) * 256 + (u & 7);
#pragma unroll
        for (int mt = 0; mt < 4; ++mt) {
#pragma unroll
            for (int r = 0; r < 4; ++r) {
                float v = ai[mt][nt][r] + bi;
                float w = 2.f * tanh_fast(v);
                const int addr = A0i + (mt >> 1) * 512 +
                                 ((mt & 1) * 16 + kq * 4 + r) * 8;
                state[addr] = f2h(v);
                state[addr + 16384] = f2h(w);
            }
        }
    }

    // ---------------- 8 implicit layers (32x32x16 MFMA) ----------------
    const int uu = wave * 32 + cl;        // this lane's output column u
    const int A0e = (uu >> 4) * 1024 + ((uu >> 3) & 1) * 256 + (uu & 7);
    for (int L = 0; L < 8; ++L) {
        const float ccv0 = cc[L * 512 + uu];
        const float ccv1 = cc[L * 512 + 256 + uu];
        f32x16 acc00, acc01, acc10, acc11;
#pragma unroll
        for (int j = 0; j < 16; ++j) {
            acc00[j] = 0.f; acc01[j] = 0.f; acc10[j] = 0.f; acc11[j] = 0.f;
        }
        __syncthreads();   // state ready
#pragma unroll
        for (int ks = 0; ks < 32; ++ks) {
            const int cur = ks & 1, nxt = cur ^ 1;
            if (ks < 31) {             // prefetch next K-step (2 x 16B)
                B[nxt][0] = *(const half8*)(bp0 + (ks + 1) * 512);
                B[nxt][1] = *(const half8*)(bp1 + (ks + 1) * 512);
            } else {                   // prefetch next layer's ks=0 across epilogue
                bp0 += 262144; bp1 += 262144;
                if (L < 7) {
                    B[nxt][0] = *(const half8*)bp0;
                    B[nxt][1] = *(const half8*)bp1;
                }
            }
            half8 af0 = *(const half8*)&state[ks * 1024 + lane * 8];
            half8 af1 = *(const half8*)&state[ks * 1024 + 512 + lane * 8];
            acc00 = __builtin_amdgcn_mfma_f32_32x32x16_f16(af0, B[cur][0], acc00, 0, 0, 0);
            acc10 = __builtin_amdgcn_mfma_f32_32x32x16_f16(af1, B[cur][0], acc10, 0, 0, 0);
            acc01 = __builtin_amdgcn_mfma_f32_32x32x16_f16(af0, B[cur][1], acc01, 0, 0, 0);
            acc11 = __builtin_amdgcn_mfma_f32_32x32x16_f16(af1, B[cur][1], acc11, 0, 0, 0);
        }
        __syncthreads();   // all state reads done; safe to overwrite
        // epilogue: lane owns col u for all 64 rows; z0/z1 in-thread
#pragma unroll
        for (int rt = 0; rt < 2; ++rt) {
#pragma unroll
            for (int j = 0; j < 16; ++j) {
                const int rowt = (j & 3) + 8 * (j >> 2) + 4 * lh;
                const int addr = A0e + rt * 512 + rowt * 8;
                float z0 = (rt ? acc10[j] : acc00[j]) + ccv0;
                float z1 = (rt ? acc11[j] : acc01[j]) + ccv1;
                float tv = tanh_fast(z0);
                state[addr] = f2h(z0);
                state[addr + 16384] = f2h(z1 + tv);
            }
        }
    }

    // ---------------- output stage: out = v0 @ W_out + b_out (32x32x16) ----
    __syncthreads();
    if (wave < 2) {
        f32x16 oa;
#pragma unroll
        for (int j = 0; j < 16; ++j) oa[j] = 0.f;
        const u16* wp = WoT + lane * 8;
#pragma unroll
        for (int ks = 0; ks < 16; ++ks) {          // v0 = state k<256
            half8 af = *(const half8*)&state[ks * 1024 + wave * 512 + lane * 8];
            half8 bf = *(const half8*)(wp + ks * 512);
            oa = __builtin_amdgcn_mfma_f32_32x32x16_f16(af, bf, oa, 0, 0, 0);
        }
        if (cl < 10) {
            const float bv = bo[cl];
#pragma unroll
            for (int j = 0; j < 16; ++j) {
                const int m = wave * 32 + (j & 3) + 8 * (j >> 2) + 4 * lh;
                out[(size_t)(b0 + m) * 10 + cl] = oa[j] + bv;
            }
        }
    }
}

// ============================================================================
// Prep — R16 verbatim (pinned ~215us; Wc tile-layout pack verified correct).
// ============================================================================

template<int NS>
__device__ __forceinline__ float4 ldn(const float* __restrict__ p, size_t idx) {
    float4 v = *(const float4*)(p + idx);
#pragma unroll
    for (int s = 1; s < NS; ++s) {
        float4 w = *(const float4*)(p + idx + (size_t)s * HS);
        v.x += w.x; v.y += w.y; v.z += w.z; v.w += w.w;
    }
    return v;
}

template<int EPI, int KLEN, int AS, int BS, int ES, int E2S>
__device__ __forceinline__ void gemm_body(float* __restrict__ D,
        const float* __restrict__ A, const float* __restrict__ Bm,
        const float* __restrict__ E, const float* __restrict__ E2,
        const float* __restrict__ scr_r, float* __restrict__ scr_w,
        int i, int u0, int v0, int kh)
{
    __shared__ float As[16][64];
    __shared__ float Bs[16][64];
    const size_t off = (size_t)i * 65536;
    const int t  = threadIdx.x;
    const int tx = t & 15, ty = t >> 4;
    const int lk = t >> 4, lv = (t & 15) << 2;

    float ca = 0.f, cb = 0.f;
    if (EPI == 3 || EPI == 4) {        // NS seed coefficients from rowsum parts
        float* red = &As[0][0];
        {
            float s = scr_r[i * 1024 + t];
#pragma unroll
            for (int vt = 1; vt < 4; ++vt) s += scr_r[i * 1024 + vt * 256 + t];
            red[t] = s;
        }
        __syncthreads();
        for (int o = 128; o >= 1; o >>= 1) {
            if (t < o) red[t] = fmaxf(red[t], red[t + o]);
            __syncthreads();
        }
        const float bt_ = red[0];                  // >= lambda_max; lambda_min >= 2
        const float r = (2.f + bt_) * (2.f + bt_) / (8.f * bt_);
        const float e = (r - 1.f) / (r + 1.f);
        cb = -(1.f - e) / (2.f * bt_);
        ca = -cb * (2.f + bt_);
        __syncthreads();
    }

    const int kb = kh * KLEN;
    float acc[4][4];
#pragma unroll
    for (int m = 0; m < 4; ++m)
#pragma unroll
        for (int n = 0; n < 4; ++n) acc[m][n] = 0.f;

    float4 an = ldn<AS>(A, off + (size_t)(kb + lk) * 256 + u0 + lv);
    float4 bn = ldn<BS>(Bm, off + (size_t)(kb + lk) * 256 + v0 + lv);

    for (int k0 = 0; k0 < KLEN; k0 += 16) {
        if (k0) __syncthreads();
        *(float4*)&As[lk][lv] = an;
        *(float4*)&Bs[lk][lv] = bn;
        if (k0 < KLEN - 16) {
            an = ldn<AS>(A, off + (size_t)(kb + k0 + 16 + lk) * 256 + u0 + lv);
            bn = ldn<BS>(Bm, off + (size_t)(kb + k0 + 16 + lk) * 256 + v0 + lv);
        }
        __syncthreads();
#pragma unroll
        for (int kk = 0; kk < 16; ++kk) {
            float af[4], bf[4];
            *(float4*)&af[0] = *(const float4*)&As[kk][ty * 4];
            *(float4*)&bf[0] = *(const float4*)&Bs[kk][tx * 4];
#pragma unroll
            for (int m = 0; m < 4; ++m)
#pragma unroll
                for (int n = 0; n < 4; ++n) acc[m][n] += af[m] * bf[n];
        }
    }

    float* Dp = D + (size_t)kh * HS;
#pragma unroll
    for (int m = 0; m < 4; ++m) {
        const int u = u0 + ty * 4 + m;
        const size_t idx = off + (size_t)u * 256 + v0 + tx * 4;
        float4 r; float* rf = &r.x;
        if (EPI == 0) {
#pragma unroll
            for (int n = 0; n < 4; ++n) rf[n] = acc[m][n];
        } else if (EPI == 1) {
#pragma unroll
            for (int n = 0; n < 4; ++n)
                rf[n] = acc[m][n] + ((u == v0 + tx * 4 + n) ? 2.f : 0.f);
        } else if (EPI == 2) {
            if (kh == 0) {
                float4 e4 = ldn<ES>(E, idx); const float* ef = &e4.x;
#pragma unroll
                for (int n = 0; n < 4; ++n) rf[n] = 2.f * ef[n] - acc[m][n];
            } else {
#pragma unroll
                for (int n = 0; n < 4; ++n) rf[n] = -acc[m][n];
            }
        } else if (EPI == 3) {
            if (kh == 0) {
                float4 e4 = ldn<ES>(E, idx); const float* ef = &e4.x;
#pragma unroll
                for (int n = 0; n < 4; ++n) rf[n] = ca * ef[n] + cb * acc[m][n];
            } else {
#pragma unroll
                for (int n = 0; n < 4; ++n) rf[n] = cb * acc[m][n];
            }
        } else {   // EPI 4
            if (kh == 0) {
                float4 e4 = ldn<ES>(E, idx); const float* ef = &e4.x;
                float4 f4 = ldn<E2S>(E2, idx); const float* ff = &f4.x;
#pragma unroll
                for (int n = 0; n < 4; ++n)
                    rf[n] = 2.f * ca * ((u == v0 + tx * 4 + n) ? 1.f : 0.f)
                          + 2.f * cb * ef[n] - ca * ff[n] - cb * acc[m][n];
            } else {
#pragma unroll
                for (int n = 0; n < 4; ++n) rf[n] = -cb * acc[m][n];
            }
        }
        *(float4*)&Dp[idx] = r;
        if (EPI == 1) {                // Gershgorin rowsum partial (plain store)
            float s = fabsf(rf[0]) + fabsf(rf[1]) + fabsf(rf[2]) + fabsf(rf[3]);
            s += __shfl_xor(s, 1); s += __shfl_xor(s, 2);
            s += __shfl_xor(s, 4); s += __shfl_xor(s, 8);
            if (tx == 0) scr_w[(i * 4 + (v0 >> 6)) * 256 + u] = s;
        }
    }
}

// K1: C = B0^T B0 + 2I (unsplit, rowsum parts) | Bt | Wi pack | WoT pack
__launch_bounds__(256)
__global__ void k1_fused(const float* __restrict__ B0, const float* __restrict__ W_in,
                         const float* __restrict__ W_out,
                         float* __restrict__ C, float* __restrict__ Bt,
                         u16* __restrict__ Wi, u16* __restrict__ WoT,
                         float* __restrict__ scr)
{
    const int b = blockIdx.x;
    const int t = threadIdx.x;
    if (b < 128) {
        const int i = b >> 4, tile = b & 15;
        gemm_body<1, 256, 1, 1, 1, 1>(C, B0, B0, nullptr, nullptr,
                                      nullptr, scr, i,
                                      (tile >> 2) * 64, (tile & 3) * 64, 0);
        return;
    }
    __shared__ float tl[32][33];
    const int tx = t & 31, ty = t >> 5;   // 32 x 8
    if (b < 192) {                        // Bt transpose: 64 blocks
        const int bb = b - 128;
        const int i = bb >> 3;
        const size_t off = (size_t)i * 65536;
        const int u0 = (bb & 7) * 32;
        for (int k0 = 0; k0 < 256; k0 += 32) {
            __syncthreads();
#pragma unroll
            for (int r = 0; r < 32; r += 8)
                tl[ty + r][tx] = B0[off + (size_t)(u0 + ty + r) * 256 + k0 + tx];
            __syncthreads();
#pragma unroll
            for (int r = 0; r < 32; r += 8)
                Bt[off + (size_t)(k0 + ty + r) * 256 + u0 + tx] = tl[tx][ty + r];
        }
    } else if (b < 392) {                 // Wi pack: 200 blocks
        const int bb = b - 192;           // 25 k-tiles x 8 u-tiles
        const int k0 = (bb % 25) * 32, u0 = (bb / 25) * 32;
#pragma unroll
        for (int r = 0; r < 32; r += 8) {
            const int k = k0 + ty + r;
            tl[ty + r][tx] = (k < 784) ? W_in[(size_t)k * 256 + u0 + tx] : 0.f;
        }
        __syncthreads();
#pragma unroll
        for (int r = 0; r < 32; r += 8)
            Wi[(size_t)(u0 + ty + r) * 800 + k0 + tx] = f2h(tl[tx][ty + r]);
    } else {                              // WoT pack: [16 ks][512] B-frag order
        for (int idx = t; idx < 8192; idx += 256) {
            const int ks = idx >> 9, rr = idx & 511;
            const int l = rr >> 3, j = rr & 7;
            const int col = l & 31;
            const int k = ks * 16 + (l >> 5) * 8 + j;
            WoT[idx] = f2h((col < 10) ? W_out[(size_t)k * 10 + col] : 0.f);
        }
    }
}

// split GEMM dispatch: grid (4,4,32), z = matrix(0..7) + 8*kq (kq 0..3), K=64
template<int EPI, int AS, int BS, int ES, int E2S>
__launch_bounds__(256)
__global__ void gemmS(float* __restrict__ D, const float* __restrict__ A,
                      const float* __restrict__ Bm, const float* __restrict__ E,
                      const float* __restrict__ E2, const float* __restrict__ scr)
{
    const int z = blockIdx.z;
    gemm_body<EPI, 64, AS, BS, ES, E2S>(D, A, Bm, E, E2, scr, nullptr,
                                        z & 7, blockIdx.y * 64, blockIdx.x * 64,
                                        z >> 3);
}

// PQcc: z<16: P = M Bt (split2) | z 16..31: Q = B M (split2) | z==32: cc
__launch_bounds__(256)
__global__ void gemmPQcc(float* __restrict__ bufPQ, const float* __restrict__ M,
                         const float* __restrict__ Bt, const float* __restrict__ B0,
                         const float* __restrict__ q, float* __restrict__ cc)
{
    const int z = blockIdx.z;
    if (z < 16) {
        gemm_body<0, 128, 4, 1, 1, 1>(bufPQ, M, Bt, nullptr, nullptr, nullptr,
                nullptr, z & 7, blockIdx.y * 64, blockIdx.x * 64, (z >> 3) & 1);
        return;
    }
    if (z < 32) {
        const int zz = z - 16;
        gemm_body<0, 128, 1, 4, 1, 1>(bufPQ + 2 * (size_t)HS, Bt, M, nullptr,
                nullptr, nullptr, nullptr, zz & 7,
                blockIdx.y * 64, blockIdx.x * 64, (zz >> 3) & 1);
        return;
    }
    if (blockIdx.y != 0 || blockIdx.x >= 8) return;
    __shared__ float qs[256];
    __shared__ float vs[256];
    __shared__ float c1s[256];
    const int i = blockIdx.x;
    const int u = threadIdx.x;
    const size_t ob = (size_t)i * 65536;
    qs[u] = q[i * 256 + u];
    __syncthreads();
    float s0 = 0.f;
    for (int k = 0; k < 256; ++k) s0 += B0[ob + (size_t)k * 256 + u] * qs[k];
    vs[u] = 0.1f * s0;
    __syncthreads();
    float s = 0.f;
    for (int k = 0; k < 256; ++k) {
        const size_t mi = ob + (size_t)k * 256 + u;
        s += (M[mi] + M[mi + HS] + M[mi + 2 * (size_t)HS] + M[mi + 3 * (size_t)HS]) * vs[k];
    }
    c1s[u] = s;
    cc[i * 512 + 256 + u] = s;
    __syncthreads();
    float s2 = 0.f;
    for (int k = 0; k < 256; ++k) s2 += Bt[ob + (size_t)k * 256 + u] * c1s[k];
    cc[i * 512 + u] = 0.1f * qs[u] - s2;
}

// Wc pack into the tile layout; sums partials (P s2, Q s2, R s4, M s4)
__launch_bounds__(256)
__global__ void pack_wcomb(const float* __restrict__ P, const float* __restrict__ Q,
                           const float* __restrict__ R, const float* __restrict__ M,
                           u16* __restrict__ W)
{
    const int i = blockIdx.y;
    const int e = blockIdx.x * 256 + threadIdx.x;   // 0..262143
    const int c = e >> 9, k = e & 511;
    const size_t off = (size_t)i * 65536;
    float v;
    if (c < 256) {        // z0 row u=c: [I - R | -Q]
        if (k < 256) {
            const size_t idx = off + (size_t)c * 256 + k;
            v = ((c == k) ? 1.f : 0.f)
              - (R[idx] + R[idx + HS] + R[idx + 2 * (size_t)HS] + R[idx + 3 * (size_t)HS]);
        } else {
            const size_t idx = off + (size_t)c * 256 + (k - 256);
            v = -(Q[idx] + Q[idx + HS]);
        }
    } else {              // z1 row u=c-256: [P | M]
        const int u = c - 256;
        if (k < 256) {
            const size_t idx = off + (size_t)u * 256 + k;
            v = P[idx] + P[idx + HS];
        } else {
            const size_t idx = off + (size_t)u * 256 + (k - 256);
            v = M[idx] + M[idx + HS] + M[idx + 2 * (size_t)HS] + M[idx + 3 * (size_t)HS];
        }
    }
    // store at B-frag tile layout: tile = col-group (z0: c>>5, z1: 8+((c-256)>>5))
    const int tile = (c < 256) ? (c >> 5) : (8 + ((c - 256) >> 5));
    const int cl2 = c & 31;
    const size_t wadr = (size_t)i * 262144 + (size_t)tile * 16384
                      + (size_t)(k >> 4) * 512 + ((k >> 3) & 1) * 256 + cl2 * 8 + (k & 7);
    W[wadr] = f2h(v);
}

extern "C" void kernel_launch(void* const* d_in, const int* in_sizes, int n_in,
                              void* d_out, int out_size, void* d_ws, size_t ws_size,
                              hipStream_t stream)
{
    const float* x     = (const float*)d_in[0];
    const float* W_in  = (const float*)d_in[1];
    const float* b_in  = (const float*)d_in[2];
    const float* B0    = (const float*)d_in[3];
    const float* q     = (const float*)d_in[4];
    const float* W_out = (const float*)d_in[5];
    const float* b_out = (const float*)d_in[6];

    u16* Wc  = (u16*)d_ws;                 // 8 * 262144 u16 = 4 MB
    u16* Wi  = Wc + 8 * 262144;            // 256*800 u16
    u16* WoT = Wi + 204800;                // 8192 u16
    float* cc = (float*)(WoT + 8192);      // 8*512 floats
    float* F  = cc + 4096;
    float* Cm   = F;                       // unsplit (1 HS)
    float* Bt   = F + 1 * HS;              // unsplit (1 HS)
    float* bufY = F + 2 * HS;              // 4 HS: Y1 / Y2 / Y3 / {P,Q}
    float* bufXa = F + 6 * HS;             // 4 HS: X1 / M
    float* bufXb = F + 10 * HS;            // 4 HS: X2 / R
    float* scr  = F + 14 * HS;             // 8192 floats (rowsum partials)

    // K1: C = B0^T B0 + 2I (+rowsum parts) | Bt | Wi | WoT
    k1_fused<<<393, 256, 0, stream>>>(B0, W_in, W_out, Cm, Bt, Wi, WoT, scr);
    // NS iteration 1 with virtual X0 = aI + bC:
    gemmS<3, 1, 1, 1, 1><<<dim3(4, 4, 32), 256, 0, stream>>>(
        bufY, Cm, Cm, Cm, nullptr, scr);                    // Y1 = aC + bC^2
    gemmS<4, 1, 4, 1, 4><<<dim3(4, 4, 32), 256, 0, stream>>>(
        bufXa, Cm, bufY, Cm, bufY, scr);                    // X1 = 2X0 - X0*Y1
    // NS iteration 2:
    gemmS<0, 1, 4, 1, 1><<<dim3(4, 4, 32), 256, 0, stream>>>(
        bufY, Cm, bufXa, nullptr, nullptr, nullptr);        // Y2 = C*X1
    gemmS<2, 4, 4, 4, 1><<<dim3(4, 4, 32), 256, 0, stream>>>(
        bufXb, bufXa, bufY, bufXa, nullptr, nullptr);       // X2 = 2X1 - X1*Y2
    // NS iteration 3:
    gemmS<0, 1, 4, 1, 1><<<dim3(4, 4, 32), 256, 0, stream>>>(
        bufY, Cm, bufXb, nullptr, nullptr, nullptr);        // Y3 = C*X2
    gemmS<2, 4, 4, 4, 1><<<dim3(4, 4, 32), 256, 0, stream>>>(
        bufXa, bufXb, bufY, bufXb, nullptr, nullptr);       // M = 2X2 - X2*Y3
    // P = M B^T (s2) | Q = B M (s2) | cc:
    gemmPQcc<<<dim3(4, 4, 33), 256, 0, stream>>>(bufY, bufXa, Bt, B0, q, cc);
    // R = B P (s4):
    gemmS<0, 1, 2, 1, 1><<<dim3(4, 4, 32), 256, 0, stream>>>(
        bufXb, Bt, bufY, nullptr, nullptr, nullptr);        // R
    // pack (P=bufY, Q=bufY+2HS, R=bufXb, M=bufXa):
    pack_wcomb<<<dim3(1024, 8), 256, 0, stream>>>(
        bufY, bufY + 2 * (size_t)HS, bufXb, bufXa, Wc);

    // ---- the whole network in one kernel ----
    meganet<<<BATCH_N / 64, 512, 0, stream>>>(
        x, Wi, b_in, Wc, cc, WoT, b_out, (float*)d_out);
}